// Round 1
// baseline (112.742 us; speedup 1.0000x reference)
//
#include <hip/hip_runtime.h>
#include <math.h>

#define AFWD 0.999f
#define ONE_MINUS_A (1.0f - 0.999f)
#define KCOEF (0.999f * (1.0f - 0.999f))
#define EPSV 1e-5f

// ---------------------------------------------------------------------------
// Pass A: per (chunk c, float4-column group) compute local summaries with
// chunk-start state M=0:
//   B_mu = local mu after CH steps           (affine offset for mu map)
//   See  = sum_i a^{CH-1-i} * e_i^2          (e_i = x_i - mu_loc_{i-1})
//   Te   = sum_i e_i
// Layout of outputs: [C][L] row-major, float4 stores (coalesced).
// ---------------------------------------------------------------------------
__global__ __launch_bounds__(256) void
passA(const float* __restrict__ x, float* __restrict__ Bmu,
      float* __restrict__ See, float* __restrict__ Te, int L4, int CH) {
  int idx  = blockIdx.x * blockDim.x + threadIdx.x;
  int col4 = idx % L4;   // float4 column group
  int c    = idx / L4;   // chunk index
  const float4* xv = (const float4*)x;
  int base = c * CH * L4 + col4;

  float mu[4] = {0.f, 0.f, 0.f, 0.f};
  float s[4]  = {0.f, 0.f, 0.f, 0.f};
  float t[4]  = {0.f, 0.f, 0.f, 0.f};

#pragma unroll 4
  for (int i = 0; i < CH; ++i) {
    float4 v = xv[base + i * L4];
    float xe[4] = {v.x, v.y, v.z, v.w};
#pragma unroll
    for (int k = 0; k < 4; ++k) {
      float e = xe[k] - mu[k];
      s[k] = fmaf(AFWD, s[k], e * e);
      t[k] += e;
      mu[k] = fmaf(ONE_MINUS_A, e, mu[k]);  // mu = a*mu + (1-a)*x
    }
  }

  int o = c * L4 + col4;  // float4 index into [C][L]
  ((float4*)Bmu)[o] = make_float4(mu[0], mu[1], mu[2], mu[3]);
  ((float4*)See)[o] = make_float4(s[0], s[1], s[2], s[3]);
  ((float4*)Te)[o]  = make_float4(t[0], t[1], t[2], t[3]);
}

// ---------------------------------------------------------------------------
// Pass B: per column l, sequentially combine the C chunk summaries to get the
// exact chunk-start states (M_c, V_c). Tiny: C*L elements.
//   A     = a^CH
//   c_eg  = a^{CH-1}
//   Sgg   = a^{CH-1} * (1 - a^CH) / (1 - a)
//   sum_i a^{CH-1-i} d_i^2 = See - 2*M*c_eg*Te + M*M*Sgg
//   V_next = A*V + a(1-a)*sum ;  M_next = A*M + Bmu
// ---------------------------------------------------------------------------
__global__ __launch_bounds__(256) void
passB(const float* __restrict__ m, const float* __restrict__ var,
      const float* __restrict__ Bmu, const float* __restrict__ See,
      const float* __restrict__ Te, float* __restrict__ Ms,
      float* __restrict__ Vs, int L, int C, float A, float c_eg, float Sgg) {
  int l = blockIdx.x * blockDim.x + threadIdx.x;
  if (l >= L) return;
  float M = m[l];
  float V = var[l];
  for (int c = 0; c < C; ++c) {
    int o = c * L + l;
    Ms[o] = M;
    Vs[o] = V;
    float bmu = Bmu[o];
    float see = See[o];
    float te  = Te[o];
    float sum = fmaf(M * M, Sgg, fmaf(-2.0f * M * c_eg, te, see));
    V = fmaf(A, V, KCOEF * sum);
    M = fmaf(A, M, bmu);
  }
}

// ---------------------------------------------------------------------------
// Pass C: per (chunk, float4-column group), replay the exact reference
// recurrence starting from (M_c, V_c) and write the normalized output.
// ---------------------------------------------------------------------------
__global__ __launch_bounds__(256) void
passC(const float* __restrict__ x, const float* __restrict__ Ms,
      const float* __restrict__ Vs, float* __restrict__ out, int L4, int CH) {
  int idx  = blockIdx.x * blockDim.x + threadIdx.x;
  int col4 = idx % L4;
  int c    = idx / L4;
  const float4* xv = (const float4*)x;
  float4* ov = (float4*)out;
  int base = c * CH * L4 + col4;

  int o = c * L4 + col4;
  float4 m4 = ((const float4*)Ms)[o];
  float4 v4 = ((const float4*)Vs)[o];
  float mu[4] = {m4.x, m4.y, m4.z, m4.w};
  float vv[4] = {v4.x, v4.y, v4.z, v4.w};

#pragma unroll 4
  for (int i = 0; i < CH; ++i) {
    float4 v = xv[base + i * L4];
    float xe[4] = {v.x, v.y, v.z, v.w};
    float oe[4];
#pragma unroll
    for (int k = 0; k < 4; ++k) {
      float d = xe[k] - mu[k];
      oe[k] = d * rsqrtf(vv[k] + EPSV);           // d / sqrt(v + eps)
      vv[k] = fmaf(AFWD, vv[k], KCOEF * (d * d)); // v = a*v + a(1-a)*d^2
      mu[k] = fmaf(ONE_MINUS_A, d, mu[k]);        // mu = mu + (1-a)*d
    }
    ov[base + i * L4] = make_float4(oe[0], oe[1], oe[2], oe[3]);
  }
}

extern "C" void kernel_launch(void* const* d_in, const int* in_sizes, int n_in,
                              void* d_out, int out_size, void* d_ws, size_t ws_size,
                              hipStream_t stream) {
  const float* x   = (const float*)d_in[0];
  const float* m   = (const float*)d_in[1];
  const float* var = (const float*)d_in[2];
  float* out = (float*)d_out;

  int L  = in_sizes[1];          // 4096
  int N  = in_sizes[0] / L;      // 8192
  int L4 = L / 4;

  // Pick chunk count C: want many chunks for parallelism, bounded by scratch.
  int C = 128;
  while (C > 1 && ((size_t)5 * C * L * sizeof(float) > ws_size || (N % C) != 0))
    C >>= 1;
  int CH = N / C;

  double a = 0.999;
  float A    = (float)pow(a, (double)CH);
  float c_eg = (float)pow(a, (double)(CH - 1));
  float Sgg  = (float)(pow(a, (double)(CH - 1)) * (1.0 - pow(a, (double)CH)) / (1.0 - a));

  float* ws  = (float*)d_ws;
  size_t CL  = (size_t)C * L;
  float* Bmu = ws;
  float* See = ws + CL;
  float* Te  = ws + 2 * CL;
  float* Ms  = ws + 3 * CL;
  float* Vs  = ws + 4 * CL;

  int threadsBig = C * L4;  // one thread per (chunk, 4 columns)
  passA<<<threadsBig / 256, 256, 0, stream>>>(x, Bmu, See, Te, L4, CH);
  passB<<<(L + 255) / 256, 256, 0, stream>>>(m, var, Bmu, See, Te, Ms, Vs, L, C,
                                             A, c_eg, Sgg);
  passC<<<threadsBig / 256, 256, 0, stream>>>(x, Ms, Vs, out, L4, CH);
}

// Round 3
// 92.428 us; speedup vs baseline: 1.2198x; 1.2198x over previous
//
#include <hip/hip_runtime.h>
#include <math.h>

#define AFWD 0.999f
#define ONE_MINUS_A (1.0f - 0.999f)
#define KCOEF (0.999f * (1.0f - 0.999f))
#define EPSV 1e-5f

typedef float floatx4 __attribute__((ext_vector_type(4)));

// ---------------------------------------------------------------------------
// Pass A: per (chunk c, float4-column group) compute local summaries with
// chunk-start state M=0:
//   B_mu = local mu after CH steps           (affine offset for mu map)
//   See  = sum_i a^{CH-1-i} * e_i^2          (e_i = x_i - mu_loc_{i-1})
//   Te   = sum_i e_i
// ---------------------------------------------------------------------------
__global__ __launch_bounds__(256) void
passA(const float* __restrict__ x, float* __restrict__ Bmu,
      float* __restrict__ See, float* __restrict__ Te, int L4, int CH) {
  int idx  = blockIdx.x * blockDim.x + threadIdx.x;
  int col4 = idx % L4;   // float4 column group
  int c    = idx / L4;   // chunk index
  const floatx4* xv = (const floatx4*)x;
  int base = c * CH * L4 + col4;

  float mu[4] = {0.f, 0.f, 0.f, 0.f};
  float s[4]  = {0.f, 0.f, 0.f, 0.f};
  float t[4]  = {0.f, 0.f, 0.f, 0.f};

#pragma unroll 4
  for (int i = 0; i < CH; ++i) {
    floatx4 v = xv[base + i * L4];
#pragma unroll
    for (int k = 0; k < 4; ++k) {
      float e = v[k] - mu[k];
      s[k] = fmaf(AFWD, s[k], e * e);
      t[k] += e;
      mu[k] = fmaf(ONE_MINUS_A, e, mu[k]);  // mu = a*mu + (1-a)*x
    }
  }

  int o = c * L4 + col4;  // float4 index into [C][L]
  floatx4 om = {mu[0], mu[1], mu[2], mu[3]};
  floatx4 os = {s[0], s[1], s[2], s[3]};
  floatx4 ot = {t[0], t[1], t[2], t[3]};
  ((floatx4*)Bmu)[o] = om;
  ((floatx4*)See)[o] = os;
  ((floatx4*)Te)[o]  = ot;
}

// ---------------------------------------------------------------------------
// Pass B (parallel): one block per column, blockDim.x == C. Two weighted
// Hillis-Steele scans over the chunk dim replace the serial 128-step loop.
//   M_c = A^c*M0 + sum_{j<c} A^{c-1-j} * bmu_j
//   w_j = KCOEF*(see_j - 2*c_eg*te_j*M_j + Sgg*M_j^2)
//   V_c = A^c*V0 + sum_{j<c} A^{c-1-j} * w_j
// Stores the exclusive (chunk-start) states Ms/Vs.
// ---------------------------------------------------------------------------
__device__ __forceinline__ float
weighted_scan_incl(float u, float A, int c, int C, float* sm) {
  float p = u;
  float w = A;  // level weight A^(2^k)
  for (int off = 1; off < C; off <<= 1) {
    __syncthreads();
    sm[c] = p;
    __syncthreads();
    if (c >= off) p = fmaf(w, sm[c - off], p);
    w *= w;
  }
  return p;  // P_c = sum_{j<=c} A^{c-j} u_j
}

__global__ void
passB_scan(const float* __restrict__ m, const float* __restrict__ var,
           const float* __restrict__ Bmu, const float* __restrict__ See,
           const float* __restrict__ Te, float* __restrict__ Ms,
           float* __restrict__ Vs, int L, int C, float A, float c_eg,
           float Sgg) {
  extern __shared__ float sm[];  // C floats
  int l = blockIdx.x;
  int c = threadIdx.x;
  int o = c * L + l;

  float bmu = Bmu[o];
  float see = See[o];
  float te  = Te[o];
  float M0 = m[l];
  float V0 = var[l];

  // A^c via binary exponentiation (predicated, no divergence)
  float Ac = 1.0f, Ap = A;
#pragma unroll
  for (int b = 0; b < 10; ++b) {
    if (c & (1 << b)) Ac *= Ap;
    Ap *= Ap;
  }

  // scan 1: mu offsets
  float p = weighted_scan_incl(bmu, A, c, C, sm);
  __syncthreads();
  sm[c] = p;
  __syncthreads();
  float M = fmaf(Ac, M0, (c > 0) ? sm[c - 1] : 0.0f);  // chunk-start mu

  // scan 2: variance contributions (depends on M)
  float w = KCOEF * fmaf(M * M, Sgg, fmaf(-2.0f * c_eg * M, te, see));
  float q = weighted_scan_incl(w, A, c, C, sm);
  __syncthreads();
  sm[c] = q;
  __syncthreads();
  float V = fmaf(Ac, V0, (c > 0) ? sm[c - 1] : 0.0f);  // chunk-start var

  Ms[o] = M;
  Vs[o] = V;
}

// ---------------------------------------------------------------------------
// Pass C: per (chunk, float4-column group), replay the exact reference
// recurrence starting from (M_c, V_c) and write the normalized output.
// Nontemporal stores for out: don't evict x (L3-resident from passA).
// ---------------------------------------------------------------------------
__global__ __launch_bounds__(256) void
passC(const float* __restrict__ x, const float* __restrict__ Ms,
      const float* __restrict__ Vs, float* __restrict__ out, int L4, int CH) {
  int idx  = blockIdx.x * blockDim.x + threadIdx.x;
  int col4 = idx % L4;
  int c    = idx / L4;
  const floatx4* xv = (const floatx4*)x;
  floatx4* ov = (floatx4*)out;
  int base = c * CH * L4 + col4;

  int o = c * L4 + col4;
  floatx4 m4 = ((const floatx4*)Ms)[o];
  floatx4 v4 = ((const floatx4*)Vs)[o];
  float mu[4] = {m4[0], m4[1], m4[2], m4[3]};
  float vv[4] = {v4[0], v4[1], v4[2], v4[3]};

#pragma unroll 4
  for (int i = 0; i < CH; ++i) {
    floatx4 v = xv[base + i * L4];
    floatx4 oe;
#pragma unroll
    for (int k = 0; k < 4; ++k) {
      float d = v[k] - mu[k];
      oe[k] = d * rsqrtf(vv[k] + EPSV);           // d / sqrt(v + eps)
      vv[k] = fmaf(AFWD, vv[k], KCOEF * (d * d)); // v = a*v + a(1-a)*d^2
      mu[k] = fmaf(ONE_MINUS_A, d, mu[k]);        // mu = mu + (1-a)*d
    }
    __builtin_nontemporal_store(oe, &ov[base + i * L4]);
  }
}

extern "C" void kernel_launch(void* const* d_in, const int* in_sizes, int n_in,
                              void* d_out, int out_size, void* d_ws, size_t ws_size,
                              hipStream_t stream) {
  const float* x   = (const float*)d_in[0];
  const float* m   = (const float*)d_in[1];
  const float* var = (const float*)d_in[2];
  float* out = (float*)d_out;

  int L  = in_sizes[1];          // 4096
  int N  = in_sizes[0] / L;      // 8192
  int L4 = L / 4;

  int C = 128;
  while (C > 1 && ((size_t)5 * C * L * sizeof(float) > ws_size || (N % C) != 0))
    C >>= 1;
  int CH = N / C;

  double a = 0.999;
  float A    = (float)pow(a, (double)CH);
  float c_eg = (float)pow(a, (double)(CH - 1));
  float Sgg  = (float)(pow(a, (double)(CH - 1)) * (1.0 - pow(a, (double)CH)) / (1.0 - a));

  float* ws  = (float*)d_ws;
  size_t CL  = (size_t)C * L;
  float* Bmu = ws;
  float* See = ws + CL;
  float* Te  = ws + 2 * CL;
  float* Ms  = ws + 3 * CL;
  float* Vs  = ws + 4 * CL;

  int threadsBig = C * L4;  // one thread per (chunk, 4 columns)
  passA<<<threadsBig / 256, 256, 0, stream>>>(x, Bmu, See, Te, L4, CH);
  passB_scan<<<L, C, C * sizeof(float), stream>>>(m, var, Bmu, See, Te, Ms, Vs,
                                                  L, C, A, c_eg, Sgg);
  passC<<<threadsBig / 256, 256, 0, stream>>>(x, Ms, Vs, out, L4, CH);
}